// Round 1
// baseline (214.472 us; speedup 1.0000x reference)
//
#include <hip/hip_runtime.h>
#include <hip/hip_bf16.h>
#include <math.h>

// ScaledDotProductAttention (IBM commonsense-rl masked_softmax semantics)
// B=16, Lq=Lk=2048, D=64, TEMPERATURE=8.
// Two-pass MFMA flash-style: pass1 = online (max,sum) per q-row,
// pass2 = recompute scores, write normalized attn, PV accumulate.
// Swapped QK^T (A=K, B=Q) so each lane's q-index is lane&15 and the row
// reduction is in-lane + shfl_xor(16,32).

typedef __bf16 bf16x8v __attribute__((ext_vector_type(8)));
typedef __bf16 bf16x4v __attribute__((ext_vector_type(4)));
typedef __bf16 bf16x2v __attribute__((ext_vector_type(2)));
typedef float  f32x4   __attribute__((ext_vector_type(4)));
typedef int    i32x4   __attribute__((ext_vector_type(4)));

#define B_  16
#define L_  2048
#define D_  64

__global__ __launch_bounds__(256, 2)
void sdpa_kernel(const float* __restrict__ qg,
                 const float* __restrict__ kg,
                 const float* __restrict__ vg,
                 const int*   __restrict__ mg,
                 float* __restrict__ outg,    // [B][L][D]
                 float* __restrict__ attng)   // [B][L][L]
{
    // LDS: K tile (bf16, padded stride 72), transposed V tile, per-wave P
    // tiles, and pass1->pass2 mask nibble cache. Total 60416 B.
    __shared__ __bf16 Kt[64][72];
    __shared__ __bf16 Vt[64][72];            // Vt[d][k]
    __shared__ __bf16 Pw[4][16][72];         // per-wave P[q][k]
    __shared__ unsigned char Mb[4][512][16]; // [wave][k/4][q] nibble

    const int t  = threadIdx.x;
    const int w  = t >> 6;        // wave 0..3
    const int l  = t & 63;        // lane
    const int lq = l & 15;        // q-col within wave tile (C/D col), also A-row
    const int g  = l >> 4;        // lane group 0..3

    const int b  = blockIdx.x >> 5;
    const int q0 = (blockIdx.x & 31) * 64;
    const int qi = q0 + w*16 + lq;           // this lane's q row (S phase)

    const size_t kvbase = (size_t)b * L_ * D_;
    const size_t mrow   = ((size_t)b * L_ + qi) * L_;

    // ---- Q fragments (B operand), 1/TEMPERATURE folded in (exact /8) ----
    bf16x8v qf0, qf1;
    {
        const float* qrow = qg + ((size_t)b*L_ + qi)*D_;
        const f32x4* p0 = (const f32x4*)(qrow + g*8);
        const f32x4* p1 = (const f32x4*)(qrow + 32 + g*8);
        f32x4 x0 = p0[0], x1 = p0[1], x2 = p1[0], x3 = p1[1];
        #pragma unroll
        for (int j = 0; j < 4; ++j) {
            qf0[j]   = (__bf16)(x0[j] * 0.125f);
            qf0[4+j] = (__bf16)(x1[j] * 0.125f);
            qf1[j]   = (__bf16)(x2[j] * 0.125f);
            qf1[4+j] = (__bf16)(x3[j] * 0.125f);
        }
    }

    float rM = -INFINITY;   // running masked max (masked entries contribute 0)
    float rS = 0.f;         // running masked exp-sum

    // ======================= PASS 1: max & sum =======================
    for (int kc = 0; kc < 32; ++kc) {
        {   // stage K chunk [64][64] fp32 -> bf16 LDS
            const int r  = t >> 2;
            const int c0 = (t & 3) * 16;
            const f32x4* src = (const f32x4*)(kg + kvbase + (size_t)(kc*64 + r)*D_ + c0);
            f32x4 x0 = src[0], x1 = src[1], x2 = src[2], x3 = src[3];
            bf16x8v h0, h1;
            #pragma unroll
            for (int j = 0; j < 4; ++j) {
                h0[j] = (__bf16)x0[j]; h0[4+j] = (__bf16)x1[j];
                h1[j] = (__bf16)x2[j]; h1[4+j] = (__bf16)x3[j];
            }
            *(bf16x8v*)&Kt[r][c0]   = h0;
            *(bf16x8v*)&Kt[r][c0+8] = h1;
        }
        __syncthreads();

        #pragma unroll
        for (int sub = 0; sub < 4; ++sub) {
            bf16x8v a0 = *(const bf16x8v*)&Kt[sub*16 + lq][g*8];
            bf16x8v a1 = *(const bf16x8v*)&Kt[sub*16 + lq][32 + g*8];
            f32x4 s = {0.f, 0.f, 0.f, 0.f};
            s = __builtin_amdgcn_mfma_f32_16x16x32_bf16(a0, qf0, s, 0, 0, 0);
            s = __builtin_amdgcn_mfma_f32_16x16x32_bf16(a1, qf1, s, 0, 0, 0);
            // lane holds S[k = kc*64+sub*16+g*4+r][q = qi], r=0..3

            const int k0 = kc*64 + sub*16 + g*4;
            i32x4 mv = *(const i32x4*)(mg + mrow + k0);
            Mb[w][kc*16 + sub*4 + g][lq] =
                (unsigned char)((mv[0]?1:0)|(mv[1]?2:0)|(mv[2]?4:0)|(mv[3]?8:0));

            float mf0 = mv[0] ? 1.f : 0.f;
            float mf1 = mv[1] ? 1.f : 0.f;
            float mf2 = mv[2] ? 1.f : 0.f;
            float mf3 = mv[3] ? 1.f : 0.f;
            float x0 = fminf(fmaxf(s[0], -15.f), 15.f) * mf0;
            float x1 = fminf(fmaxf(s[1], -15.f), 15.f) * mf1;
            float x2 = fminf(fmaxf(s[2], -15.f), 15.f) * mf2;
            float x3 = fminf(fmaxf(s[3], -15.f), 15.f) * mf3;

            float tm = fmaxf(fmaxf(x0, x1), fmaxf(x2, x3));
            float nm = fmaxf(rM, tm);
            float cr = __expf(rM - nm);          // exp(-inf)=0 on first tile
            rS = rS*cr + mf0*__expf(x0 - nm) + mf1*__expf(x1 - nm)
                       + mf2*__expf(x2 - nm) + mf3*__expf(x3 - nm);
            rM = nm;
        }
        __syncthreads();
    }

    // merge the 4 lanes (xor 16, 32) that share a q row
    #pragma unroll
    for (int off = 16; off < 64; off <<= 1) {
        float Mo = __shfl_xor(rM, off, 64);
        float So = __shfl_xor(rS, off, 64);
        float nm = fmaxf(rM, Mo);
        rS = rS*__expf(rM - nm) + So*__expf(Mo - nm);
        rM = nm;
    }
    const float inv = 1.f / (rS + 1e-6f);

    // ======================= PASS 2: attn + PV =======================
    f32x4 acc[4];
    #pragma unroll
    for (int i = 0; i < 4; ++i) acc[i] = (f32x4){0.f, 0.f, 0.f, 0.f};

    for (int kc = 0; kc < 32; ++kc) {
        __syncthreads();   // previous iter's LDS readers done
        {   // stage K chunk (identical to pass 1 -> bitwise-same scores)
            const int r  = t >> 2;
            const int c0 = (t & 3) * 16;
            const f32x4* src = (const f32x4*)(kg + kvbase + (size_t)(kc*64 + r)*D_ + c0);
            f32x4 x0 = src[0], x1 = src[1], x2 = src[2], x3 = src[3];
            bf16x8v h0, h1;
            #pragma unroll
            for (int j = 0; j < 4; ++j) {
                h0[j] = (__bf16)x0[j]; h0[4+j] = (__bf16)x1[j];
                h1[j] = (__bf16)x2[j]; h1[4+j] = (__bf16)x3[j];
            }
            *(bf16x8v*)&Kt[r][c0]   = h0;
            *(bf16x8v*)&Kt[r][c0+8] = h1;
        }
        {   // stage V chunk transposed: Vt[d][k] bf16
            const int kp = t & 31;      // k-pair
            const int dg = t >> 5;      // d-group of 8
            const float* r0 = vg + kvbase + (size_t)(kc*64 + 2*kp)*D_ + dg*8;
            const f32x4* s0 = (const f32x4*)r0;
            const f32x4* s1 = (const f32x4*)(r0 + D_);
            f32x4 a0 = s0[0], a1 = s0[1], b0 = s1[0], b1 = s1[1];
            #pragma unroll
            for (int j = 0; j < 4; ++j) {
                bf16x2v p0; p0[0] = (__bf16)a0[j]; p0[1] = (__bf16)b0[j];
                *(bf16x2v*)&Vt[dg*8 + j][2*kp] = p0;
                bf16x2v p1; p1[0] = (__bf16)a1[j]; p1[1] = (__bf16)b1[j];
                *(bf16x2v*)&Vt[dg*8 + 4 + j][2*kp] = p1;
            }
        }
        __syncthreads();

        // recompute S, write normalized attn, stash P (bf16) in LDS
        #pragma unroll
        for (int sub = 0; sub < 4; ++sub) {
            bf16x8v a0 = *(const bf16x8v*)&Kt[sub*16 + lq][g*8];
            bf16x8v a1 = *(const bf16x8v*)&Kt[sub*16 + lq][32 + g*8];
            f32x4 s = {0.f, 0.f, 0.f, 0.f};
            s = __builtin_amdgcn_mfma_f32_16x16x32_bf16(a0, qf0, s, 0, 0, 0);
            s = __builtin_amdgcn_mfma_f32_16x16x32_bf16(a1, qf1, s, 0, 0, 0);

            const int k0 = kc*64 + sub*16 + g*4;
            unsigned mb = Mb[w][kc*16 + sub*4 + g][lq];
            float mf0 = (mb & 1u) ? 1.f : 0.f;
            float mf1 = (mb & 2u) ? 1.f : 0.f;
            float mf2 = (mb & 4u) ? 1.f : 0.f;
            float mf3 = (mb & 8u) ? 1.f : 0.f;
            float x0 = fminf(fmaxf(s[0], -15.f), 15.f) * mf0;
            float x1 = fminf(fmaxf(s[1], -15.f), 15.f) * mf1;
            float x2 = fminf(fmaxf(s[2], -15.f), 15.f) * mf2;
            float x3 = fminf(fmaxf(s[3], -15.f), 15.f) * mf3;

            float p0 = __expf(x0 - rM) * mf0 * inv;
            float p1 = __expf(x1 - rM) * mf1 * inv;
            float p2 = __expf(x2 - rM) * mf2 * inv;
            float p3 = __expf(x3 - rM) * mf3 * inv;

            f32x4 pv = {p0, p1, p2, p3};
            *(f32x4*)(attng + mrow + k0) = pv;

            bf16x4v pb;
            pb[0] = (__bf16)p0; pb[1] = (__bf16)p1;
            pb[2] = (__bf16)p2; pb[3] = (__bf16)p3;
            *(bf16x4v*)&Pw[w][lq][sub*16 + g*4] = pb;
        }
        __syncthreads();   // P tiles visible (cross-lane within wave)

        // PV: A = P[q][k], B = V[k][d] (from Vt[d][k]); acc D[q][d]
        #pragma unroll
        for (int ks = 0; ks < 2; ++ks) {
            bf16x8v pa = *(const bf16x8v*)&Pw[w][lq][ks*32 + g*8];
            #pragma unroll
            for (int dt = 0; dt < 4; ++dt) {
                bf16x8v vb = *(const bf16x8v*)&Vt[dt*16 + lq][ks*32 + g*8];
                acc[dt] = __builtin_amdgcn_mfma_f32_16x16x32_bf16(pa, vb, acc[dt], 0, 0, 0);
            }
        }
    }

    // epilogue: acc D-layout = row q-local (g*4+r), col d (dt*16+lq)
    #pragma unroll
    for (int dt = 0; dt < 4; ++dt) {
        #pragma unroll
        for (int r = 0; r < 4; ++r) {
            outg[((size_t)b*L_ + (q0 + w*16 + g*4 + r))*D_ + dt*16 + lq] = acc[dt][r];
        }
    }
}

extern "C" void kernel_launch(void* const* d_in, const int* in_sizes, int n_in,
                              void* d_out, int out_size, void* d_ws, size_t ws_size,
                              hipStream_t stream) {
    (void)in_sizes; (void)n_in; (void)out_size; (void)d_ws; (void)ws_size;
    const float* q  = (const float*)d_in[0];
    const float* k  = (const float*)d_in[1];
    const float* v  = (const float*)d_in[2];
    const int*   m  = (const int*)d_in[3];
    float* out  = (float*)d_out;
    float* attn = out + (size_t)B_ * L_ * D_;   // outputs concatenated
    dim3 grid(B_ * (L_ / 64));   // 512 blocks
    dim3 block(256);
    hipLaunchKernelGGL(sdpa_kernel, grid, block, 0, stream, q, k, v, m, out, attn);
}

// Round 2
// 189.647 us; speedup vs baseline: 1.1309x; 1.1309x over previous
//
#include <hip/hip_runtime.h>
#include <hip/hip_bf16.h>
#include <math.h>

// ScaledDotProductAttention, masked_softmax semantics (clip ±15, mask-mult,
// exp(x - max), re-mask, /(sum+1e-6)). B=16, L=2048, D=64, TEMP=8.
//
// Round-2 structure:
//  - Fixed softmax shift M'=15 (valid since x<=15 after clip; perturbs p by a
//    uniform ~0.19% via the 1e-6 term -- far under tolerance). Pass 1 is now a
//    pure masked exp-sum; no max tracking, no rescale.
//  - Register-prefetch pipeline: issue next K/V tile's global loads before
//    computing the current tile (hides HBM latency; occupancy is capped at
//    2 blocks/CU by grid size, so ILP must do the hiding).
//  - XOR-swizzled LDS (byte ^= (row&7)<<4, 128B row stride) for K/V/P tiles:
//    conflict-free ds_read_b128 / writes (was 8-way with +8 pad).
//  - Mask cached pass1->pass2 as packed u16 bits in LDS (16 KB), per-lane slot.
//  - XCD-grouped block remap: each XCD's L2 sees only 2 batches' K/V.

typedef __bf16 bf16x8v __attribute__((ext_vector_type(8)));
typedef __bf16 bf16x4v __attribute__((ext_vector_type(4)));
typedef __bf16 bf16x2v __attribute__((ext_vector_type(2)));
typedef float  f32x4   __attribute__((ext_vector_type(4)));
typedef int    i32x4   __attribute__((ext_vector_type(4)));

#define B_  16
#define L_  2048
#define D_  64
#define NKC 32

// swizzled byte offset within a [rows][64] bf16 tile (128 B per row)
__device__ __forceinline__ int swz(int row, int colb) {
    return (row * 128 + colb) ^ ((row & 7) << 4);
}

__global__ __launch_bounds__(256, 2)
void sdpa_kernel(const float* __restrict__ qg,
                 const float* __restrict__ kg,
                 const float* __restrict__ vg,
                 const int*   __restrict__ mg,
                 float* __restrict__ outg,    // [B][L][D]
                 float* __restrict__ attng)   // [B][L][L]
{
    __shared__ __align__(16) char KtB[8192];          // K tile bf16 [64][64] swz
    __shared__ __align__(16) char VtB[8192];          // V^T tile bf16 [d][k] swz
    __shared__ __align__(16) char PwB[4][2048];       // per-wave P [16][64] swz
    __shared__ unsigned short Ml[NKC][256];           // mask bits [kc][thread]

    const int t  = threadIdx.x;
    const int w  = t >> 6;        // wave
    const int l  = t & 63;
    const int lq = l & 15;        // q within wave tile (MFMA col / A row)
    const int g  = l >> 4;        // 4-lane group

    // XCD-grouping remap: 512 blocks = 8 XCDs x 64; XCD x gets batches 2x,2x+1
    const int bid  = blockIdx.x;
    const int virt = (bid & 7) * 64 + (bid >> 3);
    const int b  = virt >> 5;
    const int q0 = (virt & 31) * 64;
    const int qi = q0 + w * 16 + lq;

    const size_t kvbase = (size_t)b * (L_ * D_);
    const size_t mrow   = ((size_t)b * L_ + qi) * L_;

    // ---- Q fragments (B operand), 1/8 temperature folded in ----
    bf16x8v qf0, qf1;
    {
        const float* qrow = qg + ((size_t)b * L_ + qi) * D_;
        const f32x4* p0 = (const f32x4*)(qrow + g * 8);
        const f32x4* p1 = (const f32x4*)(qrow + 32 + g * 8);
        f32x4 x0 = p0[0], x1 = p0[1], x2 = p1[0], x3 = p1[1];
        #pragma unroll
        for (int j = 0; j < 4; ++j) {
            qf0[j]     = (__bf16)(x0[j] * 0.125f);
            qf0[4 + j] = (__bf16)(x1[j] * 0.125f);
            qf1[j]     = (__bf16)(x2[j] * 0.125f);
            qf1[4 + j] = (__bf16)(x3[j] * 0.125f);
        }
    }

    // ---- staging geometry + prefetch registers ----
    const int sr  = t >> 2;               // K-tile row this thread stages
    const int scb = (t & 3) * 32;         // byte col (16 bf16 = 32 B)
    const float* kbase  = kg + kvbase + (size_t)sr * D_ + (t & 3) * 16;
    const float* vbase0 = vg + kvbase + (size_t)(2 * (t & 31)) * D_ + (t >> 5) * 8;
    const int dg = t >> 5, kp = t & 31;

    f32x4 k0r, k1r, k2r, k3r, v0r, v1r, v2r, v3r;

    auto loadK = [&](int kc) {
        const f32x4* s = (const f32x4*)(kbase + (size_t)kc * (64 * D_));
        k0r = s[0]; k1r = s[1]; k2r = s[2]; k3r = s[3];
    };
    auto writeK = [&]() {
        bf16x8v h0, h1;
        #pragma unroll
        for (int j = 0; j < 4; ++j) {
            h0[j] = (__bf16)k0r[j]; h0[4 + j] = (__bf16)k1r[j];
            h1[j] = (__bf16)k2r[j]; h1[4 + j] = (__bf16)k3r[j];
        }
        *(bf16x8v*)(KtB + swz(sr, scb))      = h0;
        *(bf16x8v*)(KtB + swz(sr, scb + 16)) = h1;
    };
    auto loadV = [&](int kc) {
        const float* r0 = vbase0 + (size_t)kc * (64 * D_);
        const f32x4* s0 = (const f32x4*)r0;
        const f32x4* s1 = (const f32x4*)(r0 + D_);
        v0r = s0[0]; v1r = s0[1]; v2r = s1[0]; v3r = s1[1];
    };
    auto writeV = [&]() {   // Vt[d][k] transposed, bf16x2 per (d, k-pair)
        #pragma unroll
        for (int j = 0; j < 4; ++j) {
            bf16x2v p0; p0[0] = (__bf16)v0r[j]; p0[1] = (__bf16)v2r[j];
            *(bf16x2v*)(VtB + swz(dg * 8 + j, kp * 4)) = p0;
            bf16x2v p1; p1[0] = (__bf16)v1r[j]; p1[1] = (__bf16)v3r[j];
            *(bf16x2v*)(VtB + swz(dg * 8 + 4 + j, kp * 4)) = p1;
        }
    };

    // ======================= PASS 1: masked exp-sum =======================
    float rS = 0.f;
    loadK(0);
    for (int kc = 0; kc < NKC; ++kc) {
        __syncthreads();                 // prev compute done reading KtB
        writeK();                        // waits vmcnt for this tile's loads
        if (kc + 1 < NKC) loadK(kc + 1); // issue next tile (overlaps compute)
        __syncthreads();                 // KtB ready
        unsigned mbits = 0;
        #pragma unroll
        for (int sub = 0; sub < 4; ++sub) {
            bf16x8v a0 = *(const bf16x8v*)(KtB + swz(sub * 16 + lq, g * 16));
            bf16x8v a1 = *(const bf16x8v*)(KtB + swz(sub * 16 + lq, 64 + g * 16));
            f32x4 s = {0.f, 0.f, 0.f, 0.f};
            s = __builtin_amdgcn_mfma_f32_16x16x32_bf16(a0, qf0, s, 0, 0, 0);
            s = __builtin_amdgcn_mfma_f32_16x16x32_bf16(a1, qf1, s, 0, 0, 0);
            // lane holds S[k = kc*64+sub*16+g*4+r][q = qi]
            i32x4 mv = *(const i32x4*)(mg + mrow + kc * 64 + sub * 16 + g * 4);
            #pragma unroll
            for (int r = 0; r < 4; ++r) {
                bool mm = (mv[r] != 0);
                mbits |= mm ? (1u << (sub * 4 + r)) : 0u;
                float y = mm ? (fminf(fmaxf(s[r], -15.f), 15.f) - 15.f) : -1e30f;
                rS += __expf(y);         // exp(-1e30) = 0
            }
        }
        Ml[kc][t] = (unsigned short)mbits;   // per-lane slot, no barrier needed
    }

    // issue pass-2 first tiles, then reduce (overlap load latency)
    loadK(0); loadV(0);
    rS += __shfl_xor(rS, 16, 64);
    rS += __shfl_xor(rS, 32, 64);
    const float inv = 1.f / (rS + 1e-6f);

    // ======================= PASS 2: attn + PV =======================
    f32x4 acc[4];
    #pragma unroll
    for (int i = 0; i < 4; ++i) acc[i] = (f32x4){0.f, 0.f, 0.f, 0.f};

    for (int kc = 0; kc < NKC; ++kc) {
        __syncthreads();                 // prev compute done reading Kt/Vt
        writeK(); writeV();
        if (kc + 1 < NKC) { loadK(kc + 1); loadV(kc + 1); }
        __syncthreads();                 // tiles ready
        const unsigned mbits = Ml[kc][t];
        #pragma unroll
        for (int sub = 0; sub < 4; ++sub) {
            bf16x8v a0 = *(const bf16x8v*)(KtB + swz(sub * 16 + lq, g * 16));
            bf16x8v a1 = *(const bf16x8v*)(KtB + swz(sub * 16 + lq, 64 + g * 16));
            f32x4 s = {0.f, 0.f, 0.f, 0.f};
            s = __builtin_amdgcn_mfma_f32_16x16x32_bf16(a0, qf0, s, 0, 0, 0);
            s = __builtin_amdgcn_mfma_f32_16x16x32_bf16(a1, qf1, s, 0, 0, 0);

            f32x4 pv; bf16x4v pb;
            #pragma unroll
            for (int r = 0; r < 4; ++r) {
                bool mm = (mbits >> (sub * 4 + r)) & 1u;
                float y = mm ? (fminf(fmaxf(s[r], -15.f), 15.f) - 15.f) : -1e30f;
                float p = __expf(y) * inv;
                pv[r] = p;
                pb[r] = (__bf16)p;
            }
            *(f32x4*)(attng + mrow + kc * 64 + sub * 16 + g * 4) = pv;
            *(bf16x4v*)(PwB[w] + swz(lq, (sub * 16 + g * 4) * 2)) = pb;
        }
        // PV: A = P[q][k] (per-wave LDS, same-wave RAW -> lgkmcnt only)
        #pragma unroll
        for (int ks = 0; ks < 2; ++ks) {
            bf16x8v pa = *(const bf16x8v*)(PwB[w] + swz(lq, ks * 64 + g * 16));
            #pragma unroll
            for (int dt = 0; dt < 4; ++dt) {
                bf16x8v vb = *(const bf16x8v*)(VtB + swz(dt * 16 + lq, ks * 64 + g * 16));
                acc[dt] = __builtin_amdgcn_mfma_f32_16x16x32_bf16(pa, vb, acc[dt], 0, 0, 0);
            }
        }
    }

    // epilogue: acc row = q-local (g*4+r), col = d (dt*16+lq)
    #pragma unroll
    for (int dt = 0; dt < 4; ++dt) {
        #pragma unroll
        for (int r = 0; r < 4; ++r) {
            outg[((size_t)b * L_ + (q0 + w * 16 + g * 4 + r)) * D_ + dt * 16 + lq] = acc[dt][r];
        }
    }
}

extern "C" void kernel_launch(void* const* d_in, const int* in_sizes, int n_in,
                              void* d_out, int out_size, void* d_ws, size_t ws_size,
                              hipStream_t stream) {
    (void)in_sizes; (void)n_in; (void)out_size; (void)d_ws; (void)ws_size;
    const float* q = (const float*)d_in[0];
    const float* k = (const float*)d_in[1];
    const float* v = (const float*)d_in[2];
    const int*   m = (const int*)d_in[3];
    float* out  = (float*)d_out;
    float* attn = out + (size_t)B_ * L_ * D_;
    dim3 grid(B_ * (L_ / 64));   // 512
    dim3 block(256);
    hipLaunchKernelGGL(sdpa_kernel, grid, block, 0, stream, q, k, v, m, out, attn);
}

// Round 3
// 184.831 us; speedup vs baseline: 1.1604x; 1.0261x over previous
//
#include <hip/hip_runtime.h>
#include <hip/hip_bf16.h>
#include <math.h>

// ScaledDotProductAttention, masked_softmax semantics (clip ±15, mask-mult,
// exp(x - max), re-mask, /(sum+1e-6)). B=16, L=2048, D=64, TEMP=8.
//
// Round-3 structure (on top of round-2's fixed shift M'=15, swizzled LDS,
// packed mask cache, XCD remap):
//  - Double-buffered K/V LDS tiles -> ONE barrier per K-tile (was two).
//  - Depth-1 register prefetch for K, V, and MASK (mask was the exposed
//    latency: consumed same-iteration in round 2). Two named register sets,
//    manual unroll-by-2 for static indexing.

typedef __bf16 bf16x8v __attribute__((ext_vector_type(8)));
typedef __bf16 bf16x4v __attribute__((ext_vector_type(4)));
typedef __bf16 bf16x2v __attribute__((ext_vector_type(2)));
typedef float  f32x4   __attribute__((ext_vector_type(4)));
typedef int    i32x4   __attribute__((ext_vector_type(4)));

#define B_  16
#define L_  2048
#define D_  64
#define NKC 32

// swizzled byte offset within a [rows][64] bf16 tile (128 B per row)
__device__ __forceinline__ int swz(int row, int colb) {
    return (row * 128 + colb) ^ ((row & 7) << 4);
}

__global__ __launch_bounds__(256, 2)
void sdpa_kernel(const float* __restrict__ qg,
                 const float* __restrict__ kg,
                 const float* __restrict__ vg,
                 const int*   __restrict__ mg,
                 float* __restrict__ outg,    // [B][L][D]
                 float* __restrict__ attng)   // [B][L][L]
{
    __shared__ __align__(16) char KtB[2][8192];   // K tile bf16 [64][64] swz
    __shared__ __align__(16) char VtB[2][8192];   // V^T tile bf16 [d][k] swz
    __shared__ __align__(16) char PwB[4][2048];   // per-wave P [16][64] swz
    __shared__ unsigned short Ml[NKC][256];       // mask bits [kc][thread]

    const int t  = threadIdx.x;
    const int w  = t >> 6;
    const int l  = t & 63;
    const int lq = l & 15;        // q within wave tile (MFMA col / A row)
    const int g  = l >> 4;        // 4-lane group

    // XCD-grouping remap: 512 blocks = 8 XCDs x 64; XCD x gets batches 2x,2x+1
    const int bid  = blockIdx.x;
    const int virt = (bid & 7) * 64 + (bid >> 3);
    const int b  = virt >> 5;
    const int q0 = (virt & 31) * 64;
    const int qi = q0 + w * 16 + lq;

    const size_t kvbase = (size_t)b * (L_ * D_);
    const size_t mrow   = ((size_t)b * L_ + qi) * L_;

    // ---- Q fragments (B operand), 1/8 temperature folded in ----
    bf16x8v qf0, qf1;
    {
        const float* qrow = qg + ((size_t)b * L_ + qi) * D_;
        const f32x4* p0 = (const f32x4*)(qrow + g * 8);
        const f32x4* p1 = (const f32x4*)(qrow + 32 + g * 8);
        f32x4 x0 = p0[0], x1 = p0[1], x2 = p1[0], x3 = p1[1];
        #pragma unroll
        for (int j = 0; j < 4; ++j) {
            qf0[j]     = (__bf16)(x0[j] * 0.125f);
            qf0[4 + j] = (__bf16)(x1[j] * 0.125f);
            qf1[j]     = (__bf16)(x2[j] * 0.125f);
            qf1[4 + j] = (__bf16)(x3[j] * 0.125f);
        }
    }

    // ---- staging geometry ----
    const int sr  = t >> 2;               // K-tile row this thread stages
    const int scb = (t & 3) * 32;         // byte col (16 bf16 = 32 B)
    const float* kbase  = kg + kvbase + (size_t)sr * D_ + (t & 3) * 16;
    const float* vbase0 = vg + kvbase + (size_t)(2 * (t & 31)) * D_ + (t >> 5) * 8;
    const int dg = t >> 5, kp = t & 31;

    auto loadK = [&](int kc, f32x4& a, f32x4& bb, f32x4& c, f32x4& d) {
        const f32x4* s = (const f32x4*)(kbase + (size_t)kc * (64 * D_));
        a = s[0]; bb = s[1]; c = s[2]; d = s[3];
    };
    auto writeK = [&](char* buf, f32x4 a, f32x4 bb, f32x4 c, f32x4 d) {
        bf16x8v h0, h1;
        #pragma unroll
        for (int j = 0; j < 4; ++j) {
            h0[j] = (__bf16)a[j]; h0[4 + j] = (__bf16)bb[j];
            h1[j] = (__bf16)c[j]; h1[4 + j] = (__bf16)d[j];
        }
        *(bf16x8v*)(buf + swz(sr, scb))      = h0;
        *(bf16x8v*)(buf + swz(sr, scb + 16)) = h1;
    };
    auto loadV = [&](int kc, f32x4& a, f32x4& bb, f32x4& c, f32x4& d) {
        const float* r0 = vbase0 + (size_t)kc * (64 * D_);
        const f32x4* s0 = (const f32x4*)r0;
        const f32x4* s1 = (const f32x4*)(r0 + D_);
        a = s0[0]; bb = s0[1]; c = s1[0]; d = s1[1];
    };
    auto writeV = [&](char* buf, f32x4 a, f32x4 bb, f32x4 c, f32x4 d) {
        #pragma unroll
        for (int j = 0; j < 4; ++j) {
            bf16x2v p0; p0[0] = (__bf16)a[j];  p0[1] = (__bf16)c[j];
            *(bf16x2v*)(buf + swz(dg * 8 + j, kp * 4)) = p0;
            bf16x2v p1; p1[0] = (__bf16)bb[j]; p1[1] = (__bf16)d[j];
            *(bf16x2v*)(buf + swz(dg * 8 + 4 + j, kp * 4)) = p1;
        }
    };
    auto loadM = [&](int kc, i32x4& m0, i32x4& m1, i32x4& m2, i32x4& m3) {
        const int* p = mg + mrow + kc * 64 + g * 4;
        m0 = *(const i32x4*)(p);
        m1 = *(const i32x4*)(p + 16);
        m2 = *(const i32x4*)(p + 32);
        m3 = *(const i32x4*)(p + 48);
    };

    float rS = 0.f;
    float inv = 0.f;

    auto compute1 = [&](const char* KB, int kc, i32x4 m0, i32x4 m1, i32x4 m2, i32x4 m3) {
        unsigned mbits = 0;
        float part = 0.f;
        #pragma unroll
        for (int sub = 0; sub < 4; ++sub) {
            bf16x8v a0 = *(const bf16x8v*)(KB + swz(sub * 16 + lq, g * 16));
            bf16x8v a1 = *(const bf16x8v*)(KB + swz(sub * 16 + lq, 64 + g * 16));
            f32x4 s = {0.f, 0.f, 0.f, 0.f};
            s = __builtin_amdgcn_mfma_f32_16x16x32_bf16(a0, qf0, s, 0, 0, 0);
            s = __builtin_amdgcn_mfma_f32_16x16x32_bf16(a1, qf1, s, 0, 0, 0);
            i32x4 mv = (sub == 0) ? m0 : (sub == 1) ? m1 : (sub == 2) ? m2 : m3;
            #pragma unroll
            for (int r = 0; r < 4; ++r) {
                bool mm = (mv[r] != 0);
                mbits |= mm ? (1u << (sub * 4 + r)) : 0u;
                float y = mm ? (fminf(fmaxf(s[r], -15.f), 15.f) - 15.f) : -1e30f;
                part += __expf(y);        // exp(-1e30) = 0
            }
        }
        rS += part;
        Ml[kc][t] = (unsigned short)mbits;
    };

    f32x4 acc[4];
    #pragma unroll
    for (int i = 0; i < 4; ++i) acc[i] = (f32x4){0.f, 0.f, 0.f, 0.f};

    auto compute2 = [&](const char* KB, const char* VB, int kc) {
        const unsigned mbits = Ml[kc][t];
        #pragma unroll
        for (int sub = 0; sub < 4; ++sub) {
            bf16x8v a0 = *(const bf16x8v*)(KB + swz(sub * 16 + lq, g * 16));
            bf16x8v a1 = *(const bf16x8v*)(KB + swz(sub * 16 + lq, 64 + g * 16));
            f32x4 s = {0.f, 0.f, 0.f, 0.f};
            s = __builtin_amdgcn_mfma_f32_16x16x32_bf16(a0, qf0, s, 0, 0, 0);
            s = __builtin_amdgcn_mfma_f32_16x16x32_bf16(a1, qf1, s, 0, 0, 0);
            f32x4 pv; bf16x4v pb;
            #pragma unroll
            for (int r = 0; r < 4; ++r) {
                bool mm = (mbits >> (sub * 4 + r)) & 1u;
                float y = mm ? (fminf(fmaxf(s[r], -15.f), 15.f) - 15.f) : -1e30f;
                float p = __expf(y) * inv;
                pv[r] = p; pb[r] = (__bf16)p;
            }
            *(f32x4*)(attng + mrow + kc * 64 + sub * 16 + g * 4) = pv;
            *(bf16x4v*)(PwB[w] + swz(lq, (sub * 16 + g * 4) * 2)) = pb;
        }
        #pragma unroll
        for (int ks = 0; ks < 2; ++ks) {
            bf16x8v pa = *(const bf16x8v*)(PwB[w] + swz(lq, ks * 64 + g * 16));
            #pragma unroll
            for (int dt = 0; dt < 4; ++dt) {
                bf16x8v vb = *(const bf16x8v*)(VB + swz(dt * 16 + lq, ks * 64 + g * 16));
                acc[dt] = __builtin_amdgcn_mfma_f32_16x16x32_bf16(pa, vb, acc[dt], 0, 0, 0);
            }
        }
    };

    // prefetch register sets
    f32x4 kA0, kA1, kA2, kA3, kB0, kB1, kB2, kB3;
    f32x4 vA0, vA1, vA2, vA3, vB0, vB1, vB2, vB3;
    i32x4 mA0, mA1, mA2, mA3, mB0, mB1, mB2, mB3;

    // ======================= PASS 1: masked exp-sum =======================
    loadK(0, kA0, kA1, kA2, kA3);
    loadM(0, mA0, mA1, mA2, mA3);
    writeK(KtB[0], kA0, kA1, kA2, kA3);
    loadK(1, kB0, kB1, kB2, kB3);
    __syncthreads();
    #pragma unroll 1
    for (int kc = 0; kc < NKC; kc += 2) {
        // even: compute KtB[0] (tile kc) with mask set A
        loadM(kc + 1, mB0, mB1, mB2, mB3);
        compute1(KtB[0], kc, mA0, mA1, mA2, mA3);
        writeK(KtB[1], kB0, kB1, kB2, kB3);          // K(kc+1) -> buf1
        { int kn = (kc + 2 < NKC) ? kc + 2 : NKC - 1; loadK(kn, kA0, kA1, kA2, kA3); }
        __syncthreads();
        // odd: compute KtB[1] (tile kc+1) with mask set B
        { int kn = (kc + 2 < NKC) ? kc + 2 : NKC - 1; loadM(kn, mA0, mA1, mA2, mA3); }
        compute1(KtB[1], kc + 1, mB0, mB1, mB2, mB3);
        writeK(KtB[0], kA0, kA1, kA2, kA3);          // K(kc+2) -> buf0
        { int kn = (kc + 3 < NKC) ? kc + 3 : NKC - 1; loadK(kn, kB0, kB1, kB2, kB3); }
        __syncthreads();
    }

    // issue pass-2 first tiles, then reduce (overlap load latency)
    loadK(0, kA0, kA1, kA2, kA3);
    loadV(0, vA0, vA1, vA2, vA3);
    rS += __shfl_xor(rS, 16, 64);
    rS += __shfl_xor(rS, 32, 64);
    inv = 1.f / (rS + 1e-6f);

    // ======================= PASS 2: attn + PV =======================
    writeK(KtB[0], kA0, kA1, kA2, kA3);
    writeV(VtB[0], vA0, vA1, vA2, vA3);
    loadK(1, kB0, kB1, kB2, kB3);
    loadV(1, vB0, vB1, vB2, vB3);
    __syncthreads();
    #pragma unroll 1
    for (int kc = 0; kc < NKC; kc += 2) {
        compute2(KtB[0], VtB[0], kc);
        writeK(KtB[1], kB0, kB1, kB2, kB3);
        writeV(VtB[1], vB0, vB1, vB2, vB3);
        { int kn = (kc + 2 < NKC) ? kc + 2 : NKC - 1;
          loadK(kn, kA0, kA1, kA2, kA3); loadV(kn, vA0, vA1, vA2, vA3); }
        __syncthreads();
        compute2(KtB[1], VtB[1], kc + 1);
        writeK(KtB[0], kA0, kA1, kA2, kA3);
        writeV(VtB[0], vA0, vA1, vA2, vA3);
        { int kn = (kc + 3 < NKC) ? kc + 3 : NKC - 1;
          loadK(kn, kB0, kB1, kB2, kB3); loadV(kn, vB0, vB1, vB2, vB3); }
        __syncthreads();
    }

    // epilogue: acc row = q-local (g*4+r), col = d (dt*16+lq)
    #pragma unroll
    for (int dt = 0; dt < 4; ++dt) {
        #pragma unroll
        for (int r = 0; r < 4; ++r) {
            outg[((size_t)b * L_ + (q0 + w * 16 + g * 4 + r)) * D_ + dt * 16 + lq] = acc[dt][r];
        }
    }
}

extern "C" void kernel_launch(void* const* d_in, const int* in_sizes, int n_in,
                              void* d_out, int out_size, void* d_ws, size_t ws_size,
                              hipStream_t stream) {
    (void)in_sizes; (void)n_in; (void)out_size; (void)d_ws; (void)ws_size;
    const float* q = (const float*)d_in[0];
    const float* k = (const float*)d_in[1];
    const float* v = (const float*)d_in[2];
    const int*   m = (const int*)d_in[3];
    float* out  = (float*)d_out;
    float* attn = out + (size_t)B_ * L_ * D_;
    dim3 grid(B_ * (L_ / 64));   // 512
    dim3 block(256);
    hipLaunchKernelGGL(sdpa_kernel, grid, block, 0, stream, q, k, v, m, out, attn);
}